// Round 2
// baseline (599.667 us; speedup 1.0000x reference)
//
#include <hip/hip_runtime.h>
#include <math.h>

// ---- problem constants ----
#define NB     2          // batch
#define LQ     21760      // queries
#define NQTOT  (NB * LQ)  // 43520
#define DM     256        // d_model
#define NH     8          // heads
#define DH     32         // d_head
#define NL     4          // levels
#define NP     4          // points

// vt (transposed values) level bases in floats: (NB*NH, HW_l, DH) per level
// HW: 16384, 4096, 1024, 256 ; base_l = 16*32*sum(HW_{<l})
// {0, 8388608, 10485760, 11010048}, total 11141120 floats

// ---------------------------------------------------------------------------
// Kernel 1: per-level channel transpose  (16, 32, HW) -> (16, HW, 32)
// 256 threads: 2 waves read 4 rows x 64 cols each via float4 (x-dim),
// staged through LDS, written back coalesced along channel dim.
// ---------------------------------------------------------------------------
__global__ __launch_bounds__(256) void msda_transpose(
    const float* __restrict__ in, float* __restrict__ out, int HW) {
  __shared__ float tile[32][33];
  const int nm   = blockIdx.y;
  const int pos0 = blockIdx.x * 32;
  const int tx = threadIdx.x & 31;
  const int ty = threadIdx.x >> 5;  // 0..7
  const float* ip = in  + (size_t)nm * 32 * HW;
  float*       op = out + (size_t)nm * HW * 32;
#pragma unroll
  for (int i = 0; i < 4; i++) {
    const int d = ty + i * 8;
    tile[d][tx] = ip[(size_t)d * HW + pos0 + tx];
  }
  __syncthreads();
#pragma unroll
  for (int i = 0; i < 4; i++) {
    const int r = ty + i * 8;
    op[(size_t)(pos0 + r) * 32 + tx] = tile[tx][r];
  }
}

// ---------------------------------------------------------------------------
// Kernel 2: fp32 GEMM  logits(43520x384) = Q(43520x256) @ W(256x384) + bias
// Block tile 64x64, BK=32, 256 threads, 4x4 microtile/thread.
// Block-column j0<256 reads W_off, j0>=256 reads W_attn (BN=64 divides both).
// ---------------------------------------------------------------------------
__global__ __launch_bounds__(256) void msda_gemm(
    const float* __restrict__ Q,
    const float* __restrict__ W_off, const float* __restrict__ b_off,
    const float* __restrict__ W_attn, const float* __restrict__ b_attn,
    float* __restrict__ Cout) {
  __shared__ float Ast[32][68];  // [k][row], row-stride 68 floats (16B-aligned, conflict-free)
  __shared__ float Bs[32][64];   // [k][col]

  const int t  = threadIdx.x;
  const int r0 = blockIdx.x * 64;
  const int j0 = blockIdx.y * 64;
  const int tx = t & 15, ty = t >> 4;

  const float* Bsrc; int ldb, cj;
  if (j0 < 256) { Bsrc = W_off;  ldb = 256; cj = j0; }
  else          { Bsrc = W_attn; ldb = 128; cj = j0 - 256; }

  const int arow = t >> 3, ac4 = (t & 7) * 4;
  const int brow = t >> 4, bc4 = (t & 15) * 4;

  float acc[4][4] = {};

  for (int k0 = 0; k0 < 256; k0 += 32) {
#pragma unroll
    for (int i = 0; i < 2; i++) {
      const float4 a = *reinterpret_cast<const float4*>(
          Q + (size_t)(r0 + arow + i * 32) * DM + k0 + ac4);
      Ast[ac4 + 0][arow + i * 32] = a.x;
      Ast[ac4 + 1][arow + i * 32] = a.y;
      Ast[ac4 + 2][arow + i * 32] = a.z;
      Ast[ac4 + 3][arow + i * 32] = a.w;
      *reinterpret_cast<float4*>(&Bs[brow + i * 16][bc4]) =
          *reinterpret_cast<const float4*>(
              Bsrc + (size_t)(k0 + brow + i * 16) * ldb + cj + bc4);
    }
    __syncthreads();
#pragma unroll
    for (int kk = 0; kk < 32; kk++) {
      const float4 a = *reinterpret_cast<const float4*>(&Ast[kk][ty * 4]);
      const float4 b = *reinterpret_cast<const float4*>(&Bs[kk][tx * 4]);
      const float av[4] = {a.x, a.y, a.z, a.w};
      const float bv[4] = {b.x, b.y, b.z, b.w};
#pragma unroll
      for (int i = 0; i < 4; i++)
#pragma unroll
        for (int j = 0; j < 4; j++)
          acc[i][j] = fmaf(av[i], bv[j], acc[i][j]);
    }
    __syncthreads();
  }

  const float* bias_src = (j0 < 256) ? (b_off + j0) : (b_attn + (j0 - 256));
  const float4 bias = *reinterpret_cast<const float4*>(bias_src + tx * 4);
  const float bvv[4] = {bias.x, bias.y, bias.z, bias.w};
#pragma unroll
  for (int i = 0; i < 4; i++) {
    const int row = r0 + ty * 4 + i;
    float4 o;
    o.x = acc[i][0] + bvv[0];
    o.y = acc[i][1] + bvv[1];
    o.z = acc[i][2] + bvv[2];
    o.w = acc[i][3] + bvv[3];
    *reinterpret_cast<float4*>(Cout + (size_t)row * 384 + j0 + tx * 4) = o;
  }
}

// ---------------------------------------------------------------------------
// Kernel 3: softmax + bilinear sampling + weighted sum.
// One wave (64 lanes) per query; 4 queries per 256-thread block.
// Lane u: head m = u>>3, channels d0 = (u&7)*4 .. +3 (float4).
// ---------------------------------------------------------------------------
__device__ __forceinline__ float4 msda_corner(const float* __restrict__ vp,
                                              int xx, int yy, int Wl) {
  if ((unsigned)xx < (unsigned)Wl && (unsigned)yy < (unsigned)Wl)
    return *reinterpret_cast<const float4*>(vp + ((size_t)yy * Wl + xx) * DH);
  float4 z; z.x = z.y = z.z = z.w = 0.f; return z;
}

__global__ __launch_bounds__(256) void msda_sample(
    const float* __restrict__ vt, const float* __restrict__ logits,
    const float* __restrict__ rp, float* __restrict__ out) {
  __shared__ float Ld[4][384];     // raw logits per query
  __shared__ float Ew[4][128];     // exp(attn logit - max)
  __shared__ float Aw[4][128];     // normalized attention weights
  __shared__ float Rf[4][8];       // reference points (L,2)
  __shared__ float Op[4][NH][36];  // padded offsets [m][l*9 + p*2 + c]

  const int t = threadIdx.x;
  const int w = t >> 6;   // local query (one wave per query)
  const int u = t & 63;   // lane
  const int n = blockIdx.y;
  const int q = blockIdx.x * 4 + w;
  const int qi = n * LQ + q;

  const float* lg = logits + (size_t)qi * 384;
  for (int i = u; i < 384; i += 64) Ld[w][i] = lg[i];
  if (u < 8) Rf[w][u] = rp[(size_t)qi * 8 + u];
  __syncthreads();

  // repack offsets into bank-conflict-free layout
#pragma unroll
  for (int r = 0; r < 4; r++) {
    const int j = u + 64 * r;            // 0..255
    const int m = j >> 5, rest = j & 31;
    const int l = rest >> 3, pc = rest & 7;
    Op[w][m][l * 9 + pc] = Ld[w][j];
  }
  // softmax over 16 (l,p) per head: exp pass
#pragma unroll
  for (int r = 0; r < 2; r++) {
    const int j = u + 64 * r;            // 0..127
    const int h4 = j & ~15;
    float mx = -1e30f;
#pragma unroll
    for (int i = 0; i < 16; i++) mx = fmaxf(mx, Ld[w][256 + h4 + i]);
    Ew[w][j] = __expf(Ld[w][256 + j] - mx);
  }
  __syncthreads();
#pragma unroll
  for (int r = 0; r < 2; r++) {
    const int j = u + 64 * r;
    const int h4 = j & ~15;
    float den = 0.f;
#pragma unroll
    for (int i = 0; i < 16; i++) den += Ew[w][h4 + i];
    Aw[w][j] = Ew[w][j] / den;
  }
  __syncthreads();

  const int m = u >> 3;
  const int d0 = (u & 7) * 4;
  float4 acc; acc.x = acc.y = acc.z = acc.w = 0.f;

  const size_t LB[4] = {0, 8388608, 10485760, 11010048};
#pragma unroll
  for (int l = 0; l < 4; l++) {
    const int Wl = 128 >> l;          // square levels: H == W
    const int HW = Wl * Wl;
    const float* vp = vt + LB[l] + ((size_t)(n * NH + m) * HW) * DH + d0;
    const float fx = fmaf(Rf[w][2 * l + 0], (float)Wl, -0.5f);
    const float fy = fmaf(Rf[w][2 * l + 1], (float)Wl, -0.5f);
#pragma unroll
    for (int p = 0; p < 4; p++) {
      const float ox = Op[w][m][l * 9 + 2 * p + 0];
      const float oy = Op[w][m][l * 9 + 2 * p + 1];
      const float aw = Aw[w][m * 16 + l * 4 + p];
      const float xp = fx + ox;       // == loc_x * W - 0.5
      const float yp = fy + oy;
      const float x0f = floorf(xp), y0f = floorf(yp);
      const float wx = xp - x0f, wy = yp - y0f;
      const int x0 = (int)x0f, y0 = (int)y0f;
      const float4 v00 = msda_corner(vp, x0,     y0,     Wl);
      const float4 v10 = msda_corner(vp, x0 + 1, y0,     Wl);
      const float4 v01 = msda_corner(vp, x0,     y0 + 1, Wl);
      const float4 v11 = msda_corner(vp, x0 + 1, y0 + 1, Wl);
      const float a00 = aw * (1.f - wx) * (1.f - wy);
      const float a10 = aw * wx * (1.f - wy);
      const float a01 = aw * (1.f - wx) * wy;
      const float a11 = aw * wx * wy;
      acc.x = fmaf(v00.x, a00, fmaf(v10.x, a10, fmaf(v01.x, a01, fmaf(v11.x, a11, acc.x))));
      acc.y = fmaf(v00.y, a00, fmaf(v10.y, a10, fmaf(v01.y, a01, fmaf(v11.y, a11, acc.y))));
      acc.z = fmaf(v00.z, a00, fmaf(v10.z, a10, fmaf(v01.z, a01, fmaf(v11.z, a11, acc.z))));
      acc.w = fmaf(v00.w, a00, fmaf(v10.w, a10, fmaf(v01.w, a01, fmaf(v11.w, a11, acc.w))));
    }
  }
  // channel index = m*32 + (u&7)*4 == u*4  -> coalesced float4 store
  *reinterpret_cast<float4*>(out + (size_t)qi * DM + u * 4) = acc;
}

// ---------------------------------------------------------------------------
extern "C" void kernel_launch(void* const* d_in, const int* in_sizes, int n_in,
                              void* d_out, int out_size, void* d_ws, size_t ws_size,
                              hipStream_t stream) {
  const float* query  = (const float*)d_in[0];
  const float* rp     = (const float*)d_in[1];
  const float* val[4] = {(const float*)d_in[2], (const float*)d_in[3],
                         (const float*)d_in[4], (const float*)d_in[5]};
  const float* W_off  = (const float*)d_in[6];
  const float* b_off  = (const float*)d_in[7];
  const float* W_attn = (const float*)d_in[8];
  const float* b_attn = (const float*)d_in[9];
  float* out = (float*)d_out;

  // workspace layout (floats): vt[11141120] | logits[16711680]  (~112 MB)
  float* vt     = (float*)d_ws;
  float* logits = vt + 11141120;

  const int HWs[4]   = {16384, 4096, 1024, 256};
  const size_t LB[4] = {0, 8388608, 10485760, 11010048};
  for (int l = 0; l < 4; l++) {
    dim3 g(HWs[l] / 32, 16);
    msda_transpose<<<g, 256, 0, stream>>>(val[l], vt + LB[l], HWs[l]);
  }

  msda_gemm<<<dim3(NQTOT / 64, 6), 256, 0, stream>>>(
      query, W_off, b_off, W_attn, b_attn, logits);

  msda_sample<<<dim3(LQ / 4, NB), 256, 0, stream>>>(vt, logits, rp, out);
}

// Round 4
// 359.150 us; speedup vs baseline: 1.6697x; 1.6697x over previous
//
#include <hip/hip_runtime.h>
#include <hip/hip_fp16.h>
#include <math.h>

// ---- problem constants ----
#define NB     2          // batch
#define LQ     21760     // queries
#define NQTOT  (NB * LQ)  // 43520
#define DM     256        // d_model
#define NH     8          // heads
#define DH     32         // d_head
#define NL     4          // levels
#define NP     4          // points

// vt16 (transposed fp16 values) level bases in halves: (NB*NH, HW_l, DH)
// HW: 16384, 4096, 1024, 256 ; {0, 8388608, 10485760, 11010048}, total 11141120

// ---------------------------------------------------------------------------
// Kernel 1: per-level channel transpose + fp32->fp16  (16, 32, HW) -> (16, HW, 32)
// ---------------------------------------------------------------------------
__global__ __launch_bounds__(256) void msda_transpose(
    const float* __restrict__ in, __half* __restrict__ out, int HW) {
  __shared__ float tile[32][33];
  const int nm   = blockIdx.y;
  const int pos0 = blockIdx.x * 32;
  const int tx = threadIdx.x & 31;
  const int ty = threadIdx.x >> 5;  // 0..7
  const float* ip = in + (size_t)nm * 32 * HW;
  __half2* op = reinterpret_cast<__half2*>(out + (size_t)nm * HW * 32);
#pragma unroll
  for (int i = 0; i < 4; i++) {
    const int d = ty + i * 8;
    tile[d][tx] = ip[(size_t)d * HW + pos0 + tx];
  }
  __syncthreads();
  const int h  = threadIdx.x & 15;   // half2 column (channel pair)
  const int r0 = threadIdx.x >> 4;   // 0..15
#pragma unroll
  for (int i = 0; i < 2; i++) {
    const int r = r0 + i * 16;       // position within tile
    op[(size_t)(pos0 + r) * 16 + h] =
        __floats2half2_rn(tile[2 * h][r], tile[2 * h + 1][r]);
  }
}

// ---------------------------------------------------------------------------
// Kernel 2: fp32 GEMM  logits(43520x384) = Q(43520x256) @ W(256x384) + bias
// (unchanged — awaiting its own counters)
// ---------------------------------------------------------------------------
__global__ __launch_bounds__(256) void msda_gemm(
    const float* __restrict__ Q,
    const float* __restrict__ W_off, const float* __restrict__ b_off,
    const float* __restrict__ W_attn, const float* __restrict__ b_attn,
    float* __restrict__ Cout) {
  __shared__ float Ast[32][68];
  __shared__ float Bs[32][64];

  const int t  = threadIdx.x;
  const int r0 = blockIdx.x * 64;
  const int j0 = blockIdx.y * 64;
  const int tx = t & 15, ty = t >> 4;

  const float* Bsrc; int ldb, cj;
  if (j0 < 256) { Bsrc = W_off;  ldb = 256; cj = j0; }
  else          { Bsrc = W_attn; ldb = 128; cj = j0 - 256; }

  const int arow = t >> 3, ac4 = (t & 7) * 4;
  const int brow = t >> 4, bc4 = (t & 15) * 4;

  float acc[4][4] = {};

  for (int k0 = 0; k0 < 256; k0 += 32) {
#pragma unroll
    for (int i = 0; i < 2; i++) {
      const float4 a = *reinterpret_cast<const float4*>(
          Q + (size_t)(r0 + arow + i * 32) * DM + k0 + ac4);
      Ast[ac4 + 0][arow + i * 32] = a.x;
      Ast[ac4 + 1][arow + i * 32] = a.y;
      Ast[ac4 + 2][arow + i * 32] = a.z;
      Ast[ac4 + 3][arow + i * 32] = a.w;
      *reinterpret_cast<float4*>(&Bs[brow + i * 16][bc4]) =
          *reinterpret_cast<const float4*>(
              Bsrc + (size_t)(k0 + brow + i * 16) * ldb + cj + bc4);
    }
    __syncthreads();
#pragma unroll
    for (int kk = 0; kk < 32; kk++) {
      const float4 a = *reinterpret_cast<const float4*>(&Ast[kk][ty * 4]);
      const float4 b = *reinterpret_cast<const float4*>(&Bs[kk][tx * 4]);
      const float av[4] = {a.x, a.y, a.z, a.w};
      const float bv[4] = {b.x, b.y, b.z, b.w};
#pragma unroll
      for (int i = 0; i < 4; i++)
#pragma unroll
        for (int j = 0; j < 4; j++)
          acc[i][j] = fmaf(av[i], bv[j], acc[i][j]);
    }
    __syncthreads();
  }

  const float* bias_src = (j0 < 256) ? (b_off + j0) : (b_attn + (j0 - 256));
  const float4 bias = *reinterpret_cast<const float4*>(bias_src + tx * 4);
  const float bvv[4] = {bias.x, bias.y, bias.z, bias.w};
#pragma unroll
  for (int i = 0; i < 4; i++) {
    const int row = r0 + ty * 4 + i;
    float4 o;
    o.x = acc[i][0] + bvv[0];
    o.y = acc[i][1] + bvv[1];
    o.z = acc[i][2] + bvv[2];
    o.w = acc[i][3] + bvv[3];
    *reinterpret_cast<float4*>(Cout + (size_t)row * 384 + j0 + tx * 4) = o;
  }
}

// ---------------------------------------------------------------------------
// Kernel 3: softmax + bilinear sampling + weighted sum (fp16 values).
// One wave per query; lane u: head m=u>>3, channels d0=(u&7)*4 (4 halves, 8B).
// All 16 corner loads of a level issued unconditionally (clamped coords,
// validity folded into weights) before the FMA pass -> deep MLP.
// ---------------------------------------------------------------------------
__global__ __launch_bounds__(256, 3) void msda_sample(
    const __half* __restrict__ vt, const float* __restrict__ logits,
    const float* __restrict__ rp, float* __restrict__ out) {
  __shared__ float Ld[4][384];
  __shared__ float Ew[4][128];
  __shared__ float Aw[4][128];
  __shared__ float Rf[4][8];
  __shared__ float Op[4][NH][36];

  const int t = threadIdx.x;
  const int w = t >> 6;
  const int u = t & 63;
  const int n = blockIdx.y;
  const int q = blockIdx.x * 4 + w;
  const int qi = n * LQ + q;

  const float* lg = logits + (size_t)qi * 384;
  for (int i = u; i < 384; i += 64) Ld[w][i] = lg[i];
  if (u < 8) Rf[w][u] = rp[(size_t)qi * 8 + u];
  __syncthreads();

#pragma unroll
  for (int r = 0; r < 4; r++) {
    const int j = u + 64 * r;
    const int m = j >> 5, rest = j & 31;
    const int l = rest >> 3, pc = rest & 7;
    Op[w][m][l * 9 + pc] = Ld[w][j];
  }
#pragma unroll
  for (int r = 0; r < 2; r++) {
    const int j = u + 64 * r;
    const int h4 = j & ~15;
    float mx = -1e30f;
#pragma unroll
    for (int i = 0; i < 16; i++) mx = fmaxf(mx, Ld[w][256 + h4 + i]);
    Ew[w][j] = __expf(Ld[w][256 + j] - mx);
  }
  __syncthreads();
#pragma unroll
  for (int r = 0; r < 2; r++) {
    const int j = u + 64 * r;
    const int h4 = j & ~15;
    float den = 0.f;
#pragma unroll
    for (int i = 0; i < 16; i++) den += Ew[w][h4 + i];
    Aw[w][j] = Ew[w][j] / den;
  }
  __syncthreads();

  const int m = u >> 3;
  const int d0 = (u & 7) * 4;  // halves
  float4 acc; acc.x = acc.y = acc.z = acc.w = 0.f;

  const size_t LB[4] = {0, 8388608, 10485760, 11010048};
#pragma unroll
  for (int l = 0; l < 4; l++) {
    const int Wl = 128 >> l;   // square levels
    const int HW = Wl * Wl;
    const __half* vp = vt + LB[l] + ((size_t)(n * NH + m) * HW) * DH + d0;

    const float fx = fmaf(Rf[w][2 * l + 0], (float)Wl, -0.5f);
    const float fy = fmaf(Rf[w][2 * l + 1], (float)Wl, -0.5f);

    uint2  cv[4][4];
    float  cw[4][4];
#pragma unroll
    for (int p = 0; p < 4; p++) {
      const float ox = Op[w][m][l * 9 + 2 * p + 0];
      const float oy = Op[w][m][l * 9 + 2 * p + 1];
      const float aw = Aw[w][m * 16 + l * 4 + p];
      const float xp = fx + ox;
      const float yp = fy + oy;
      const float x0f = floorf(xp), y0f = floorf(yp);
      const float wx = xp - x0f, wy = yp - y0f;
      const int x0 = (int)x0f, y0 = (int)y0f;
      const int x1 = x0 + 1,   y1 = y0 + 1;
      const float vx0 = ((unsigned)x0 < (unsigned)Wl) ? 1.f : 0.f;
      const float vx1 = ((unsigned)x1 < (unsigned)Wl) ? 1.f : 0.f;
      const float vy0 = ((unsigned)y0 < (unsigned)Wl) ? 1.f : 0.f;
      const float vy1 = ((unsigned)y1 < (unsigned)Wl) ? 1.f : 0.f;
      const int x0c = min(max(x0, 0), Wl - 1), x1c = min(max(x1, 0), Wl - 1);
      const int y0c = min(max(y0, 0), Wl - 1), y1c = min(max(y1, 0), Wl - 1);

      cw[p][0] = aw * (1.f - wx) * (1.f - wy) * vx0 * vy0;
      cw[p][1] = aw * wx * (1.f - wy) * vx1 * vy0;
      cw[p][2] = aw * (1.f - wx) * wy * vx0 * vy1;
      cw[p][3] = aw * wx * wy * vx1 * vy1;

      cv[p][0] = *reinterpret_cast<const uint2*>(vp + (y0c * Wl + x0c) * DH);
      cv[p][1] = *reinterpret_cast<const uint2*>(vp + (y0c * Wl + x1c) * DH);
      cv[p][2] = *reinterpret_cast<const uint2*>(vp + (y1c * Wl + x0c) * DH);
      cv[p][3] = *reinterpret_cast<const uint2*>(vp + (y1c * Wl + x1c) * DH);
    }
#pragma unroll
    for (int p = 0; p < 4; p++)
#pragma unroll
      for (int c = 0; c < 4; c++) {
        union { uint2 ui; __half2 h[2]; } cvt;
        cvt.ui = cv[p][c];
        const float2 lo = __half22float2(cvt.h[0]);
        const float2 hi = __half22float2(cvt.h[1]);
        const float wgt = cw[p][c];
        acc.x = fmaf(lo.x, wgt, acc.x);
        acc.y = fmaf(lo.y, wgt, acc.y);
        acc.z = fmaf(hi.x, wgt, acc.z);
        acc.w = fmaf(hi.y, wgt, acc.w);
      }
  }
  *reinterpret_cast<float4*>(out + (size_t)qi * DM + u * 4) = acc;
}

// ---------------------------------------------------------------------------
extern "C" void kernel_launch(void* const* d_in, const int* in_sizes, int n_in,
                              void* d_out, int out_size, void* d_ws, size_t ws_size,
                              hipStream_t stream) {
  const float* query  = (const float*)d_in[0];
  const float* rp     = (const float*)d_in[1];
  const float* val[4] = {(const float*)d_in[2], (const float*)d_in[3],
                         (const float*)d_in[4], (const float*)d_in[5]};
  const float* W_off  = (const float*)d_in[6];
  const float* b_off  = (const float*)d_in[7];
  const float* W_attn = (const float*)d_in[8];
  const float* b_attn = (const float*)d_in[9];
  float* out = (float*)d_out;

  // workspace: vt16[11141120 halves = 22.28MB] | logits[16711680 f32 = 66.8MB]
  __half* vt16  = (__half*)d_ws;
  float* logits = (float*)((char*)d_ws + 11141120ull * sizeof(__half));

  const int HWs[4]   = {16384, 4096, 1024, 256};
  const size_t LB[4] = {0, 8388608, 10485760, 11010048};
  for (int l = 0; l < 4; l++) {
    dim3 g(HWs[l] / 32, 16);
    msda_transpose<<<g, 256, 0, stream>>>(val[l], vt16 + LB[l], HWs[l]);
  }

  msda_gemm<<<dim3(NQTOT / 64, 6), 256, 0, stream>>>(
      query, W_off, b_off, W_attn, b_attn, logits);

  msda_sample<<<dim3(LQ / 4, NB), 256, 0, stream>>>(vt16, logits, rp, out);
}

// Round 5
// 282.743 us; speedup vs baseline: 2.1209x; 1.2702x over previous
//
#include <hip/hip_runtime.h>
#include <hip/hip_fp16.h>
#include <math.h>

// ---- problem constants ----
#define NB     2          // batch
#define LQ     21760      // queries
#define NQTOT  (NB * LQ)  // 43520
#define DM     256        // d_model
#define NH     8          // heads
#define DH     32         // d_head
#define NL     4          // levels
#define NP     4          // points

typedef __attribute__((ext_vector_type(8))) short    bf16x8;
typedef __attribute__((ext_vector_type(4))) float    f32x4;
typedef __attribute__((ext_vector_type(8))) unsigned short ushort8;

// RNE fp32 -> bf16 (bit-level, no API dependence)
__device__ __forceinline__ unsigned short f2bf(float x) {
  union { float f; unsigned int u; } c; c.f = x;
  const unsigned int lsb = (c.u >> 16) & 1u;
  c.u += 0x7fffu + lsb;
  return (unsigned short)(c.u >> 16);
}

// ---------------------------------------------------------------------------
// Kernel 1: per-level channel transpose + fp32->fp16  (16, 32, HW) -> (16, HW, 32)
// ---------------------------------------------------------------------------
__global__ __launch_bounds__(256) void msda_transpose(
    const float* __restrict__ in, __half* __restrict__ out, int HW) {
  __shared__ float tile[32][33];
  const int nm   = blockIdx.y;
  const int pos0 = blockIdx.x * 32;
  const int tx = threadIdx.x & 31;
  const int ty = threadIdx.x >> 5;  // 0..7
  const float* ip = in + (size_t)nm * 32 * HW;
  __half2* op = reinterpret_cast<__half2*>(out + (size_t)nm * HW * 32);
#pragma unroll
  for (int i = 0; i < 4; i++) {
    const int d = ty + i * 8;
    tile[d][tx] = ip[(size_t)d * HW + pos0 + tx];
  }
  __syncthreads();
  const int h  = threadIdx.x & 15;   // half2 column (channel pair)
  const int r0 = threadIdx.x >> 4;   // 0..15
#pragma unroll
  for (int i = 0; i < 2; i++) {
    const int r = r0 + i * 16;       // position within tile
    op[(size_t)(pos0 + r) * 16 + h] =
        __floats2half2_rn(tile[2 * h][r], tile[2 * h + 1][r]);
  }
}

// ---------------------------------------------------------------------------
// Kernel 1b: weights -> Wt[384][256] bf16 (transposed, W_off|W_attn fused).
// grid (12, 8): n-tile 32, k-tile 32. bx<8 -> W_off cols, else W_attn.
// ---------------------------------------------------------------------------
__global__ __launch_bounds__(256) void msda_cast_w(
    const float* __restrict__ W_off, const float* __restrict__ W_attn,
    unsigned short* __restrict__ Wt) {
  __shared__ float tile[32][33];
  const int n0 = blockIdx.x * 32;
  const int k0 = blockIdx.y * 32;
  const int tx = threadIdx.x & 31;
  const int ty = threadIdx.x >> 5;  // 0..7
#pragma unroll
  for (int i = 0; i < 4; i++) {
    const int k = k0 + ty + i * 8;
    const int n = n0 + tx;
    const float v = (blockIdx.x < 8) ? W_off[(size_t)k * 256 + n]
                                     : W_attn[(size_t)k * 128 + (n - 256)];
    tile[ty + i * 8][tx] = v;
  }
  __syncthreads();
#pragma unroll
  for (int i = 0; i < 4; i++) {
    const int nl = ty + i * 8;
    Wt[(size_t)(n0 + nl) * 256 + k0 + tx] = f2bf(tile[tx][nl]);
  }
}

// ---------------------------------------------------------------------------
// Kernel 2: bf16 MFMA GEMM  logits(43520x384) = Q @ W + bias, fp32 out.
// 128x128 tile, BK=64, 4 waves (2x2), each wave 64x64 = 4x4 frags of
// 16x16x32. Reg-staged LDS with XOR swizzle (byte ^= (row&7)<<4) so
// stride-128B ds_read_b128 fragment reads are bank-conflict-free (T2/G4).
// A staged from fp32 Q with in-register bf16 convert (no q16 buffer).
// ---------------------------------------------------------------------------
__global__ __launch_bounds__(256) void msda_gemm16(
    const float* __restrict__ Q, const unsigned short* __restrict__ Wt,
    const float* __restrict__ b_off, const float* __restrict__ b_attn,
    float* __restrict__ Cout) {
  __shared__ unsigned short sA[128 * 64];  // [m][k] bf16, swizzled
  __shared__ unsigned short sB[128 * 64];  // [n][k] bf16, swizzled

  const int t    = threadIdx.x;
  const int lane = t & 63;
  const int wid  = t >> 6;
  const int m0   = blockIdx.x * 128;
  const int n0   = blockIdx.y * 128;
  const int wm   = wid >> 1, wn = wid & 1;

  const int sr = t >> 3;  // staging row within 32-row group
  const int sc = t & 7;   // 16B chunk within 128B row

  f32x4 acc[4][4] = {};

  for (int ck = 0; ck < 4; ++ck) {
    const int k0 = ck * 64;
    // ---- stage A (fp32 -> bf16, swizzled ds_write_b128) ----
#pragma unroll
    for (int i = 0; i < 4; ++i) {
      const int m = i * 32 + sr;
      const float* src = Q + (size_t)(m0 + m) * DM + k0 + sc * 8;
      const float4 a0 = *reinterpret_cast<const float4*>(src);
      const float4 a1 = *reinterpret_cast<const float4*>(src + 4);
      ushort8 v;
      v[0] = f2bf(a0.x); v[1] = f2bf(a0.y); v[2] = f2bf(a0.z); v[3] = f2bf(a0.w);
      v[4] = f2bf(a1.x); v[5] = f2bf(a1.y); v[6] = f2bf(a1.z); v[7] = f2bf(a1.w);
      const int byte = m * 128 + ((sc * 16) ^ ((m & 7) << 4));
      *reinterpret_cast<ushort8*>(reinterpret_cast<char*>(sA) + byte) = v;
    }
    // ---- stage B (bf16 passthrough, swizzled) ----
#pragma unroll
    for (int i = 0; i < 4; ++i) {
      const int nr = i * 32 + sr;
      const ushort8 b = *reinterpret_cast<const ushort8*>(
          Wt + (size_t)(n0 + nr) * 256 + k0 + sc * 8);
      const int byte = nr * 128 + ((sc * 16) ^ ((nr & 7) << 4));
      *reinterpret_cast<ushort8*>(reinterpret_cast<char*>(sB) + byte) = b;
    }
    __syncthreads();
    // ---- compute: 2 k-slices x 16 MFMA ----
#pragma unroll
    for (int ks = 0; ks < 2; ++ks) {
      bf16x8 af[4], bfr[4];
#pragma unroll
      for (int f = 0; f < 4; ++f) {
        const int ar = wm * 64 + f * 16 + (lane & 15);
        const int ab = ar * 128 + ((ks * 64 + (lane >> 4) * 16) ^ ((ar & 7) << 4));
        af[f] = *reinterpret_cast<const bf16x8*>(
            reinterpret_cast<const char*>(sA) + ab);
        const int br = wn * 64 + f * 16 + (lane & 15);
        const int bb = br * 128 + ((ks * 64 + (lane >> 4) * 16) ^ ((br & 7) << 4));
        bfr[f] = *reinterpret_cast<const bf16x8*>(
            reinterpret_cast<const char*>(sB) + bb);
      }
#pragma unroll
      for (int mi = 0; mi < 4; ++mi)
#pragma unroll
        for (int ni = 0; ni < 4; ++ni)
          acc[mi][ni] = __builtin_amdgcn_mfma_f32_16x16x32_bf16(
              af[mi], bfr[ni], acc[mi][ni], 0, 0, 0);
    }
    __syncthreads();
  }

  // ---- epilogue: bias + fp32 store. D: col=lane&15, row=(lane>>4)*4+r ----
#pragma unroll
  for (int ni = 0; ni < 4; ++ni) {
    const int col = n0 + wn * 64 + ni * 16 + (lane & 15);
    const float bias = (col < 256) ? b_off[col] : b_attn[col - 256];
#pragma unroll
    for (int mi = 0; mi < 4; ++mi) {
      const int row0 = m0 + wm * 64 + mi * 16 + (lane >> 4) * 4;
#pragma unroll
      for (int r = 0; r < 4; ++r)
        Cout[(size_t)(row0 + r) * 384 + col] = acc[mi][ni][r] + bias;
    }
  }
}

// ---------------------------------------------------------------------------
// Kernel 3: softmax + bilinear sampling + weighted sum (fp16 values).
// (unchanged from round 4 — it left the top-5)
// ---------------------------------------------------------------------------
__global__ __launch_bounds__(256, 3) void msda_sample(
    const __half* __restrict__ vt, const float* __restrict__ logits,
    const float* __restrict__ rp, float* __restrict__ out) {
  __shared__ float Ld[4][384];
  __shared__ float Ew[4][128];
  __shared__ float Aw[4][128];
  __shared__ float Rf[4][8];
  __shared__ float Op[4][NH][36];

  const int t = threadIdx.x;
  const int w = t >> 6;
  const int u = t & 63;
  const int n = blockIdx.y;
  const int q = blockIdx.x * 4 + w;
  const int qi = n * LQ + q;

  const float* lg = logits + (size_t)qi * 384;
  for (int i = u; i < 384; i += 64) Ld[w][i] = lg[i];
  if (u < 8) Rf[w][u] = rp[(size_t)qi * 8 + u];
  __syncthreads();

#pragma unroll
  for (int r = 0; r < 4; r++) {
    const int j = u + 64 * r;
    const int m = j >> 5, rest = j & 31;
    const int l = rest >> 3, pc = rest & 7;
    Op[w][m][l * 9 + pc] = Ld[w][j];
  }
#pragma unroll
  for (int r = 0; r < 2; r++) {
    const int j = u + 64 * r;
    const int h4 = j & ~15;
    float mx = -1e30f;
#pragma unroll
    for (int i = 0; i < 16; i++) mx = fmaxf(mx, Ld[w][256 + h4 + i]);
    Ew[w][j] = __expf(Ld[w][256 + j] - mx);
  }
  __syncthreads();
#pragma unroll
  for (int r = 0; r < 2; r++) {
    const int j = u + 64 * r;
    const int h4 = j & ~15;
    float den = 0.f;
#pragma unroll
    for (int i = 0; i < 16; i++) den += Ew[w][h4 + i];
    Aw[w][j] = Ew[w][j] / den;
  }
  __syncthreads();

  const int m = u >> 3;
  const int d0 = (u & 7) * 4;  // halves
  float4 acc; acc.x = acc.y = acc.z = acc.w = 0.f;

  const size_t LB[4] = {0, 8388608, 10485760, 11010048};
#pragma unroll
  for (int l = 0; l < 4; l++) {
    const int Wl = 128 >> l;   // square levels
    const int HW = Wl * Wl;
    const __half* vp = vt + LB[l] + ((size_t)(n * NH + m) * HW) * DH + d0;

    const float fx = fmaf(Rf[w][2 * l + 0], (float)Wl, -0.5f);
    const float fy = fmaf(Rf[w][2 * l + 1], (float)Wl, -0.5f);

    uint2  cv[4][4];
    float  cw[4][4];
#pragma unroll
    for (int p = 0; p < 4; p++) {
      const float ox = Op[w][m][l * 9 + 2 * p + 0];
      const float oy = Op[w][m][l * 9 + 2 * p + 1];
      const float aw = Aw[w][m * 16 + l * 4 + p];
      const float xp = fx + ox;
      const float yp = fy + oy;
      const float x0f = floorf(xp), y0f = floorf(yp);
      const float wx = xp - x0f, wy = yp - y0f;
      const int x0 = (int)x0f, y0 = (int)y0f;
      const int x1 = x0 + 1,   y1 = y0 + 1;
      const float vx0 = ((unsigned)x0 < (unsigned)Wl) ? 1.f : 0.f;
      const float vx1 = ((unsigned)x1 < (unsigned)Wl) ? 1.f : 0.f;
      const float vy0 = ((unsigned)y0 < (unsigned)Wl) ? 1.f : 0.f;
      const float vy1 = ((unsigned)y1 < (unsigned)Wl) ? 1.f : 0.f;
      const int x0c = min(max(x0, 0), Wl - 1), x1c = min(max(x1, 0), Wl - 1);
      const int y0c = min(max(y0, 0), Wl - 1), y1c = min(max(y1, 0), Wl - 1);

      cw[p][0] = aw * (1.f - wx) * (1.f - wy) * vx0 * vy0;
      cw[p][1] = aw * wx * (1.f - wy) * vx1 * vy0;
      cw[p][2] = aw * (1.f - wx) * wy * vx0 * vy1;
      cw[p][3] = aw * wx * wy * vx1 * vy1;

      cv[p][0] = *reinterpret_cast<const uint2*>(vp + (y0c * Wl + x0c) * DH);
      cv[p][1] = *reinterpret_cast<const uint2*>(vp + (y0c * Wl + x1c) * DH);
      cv[p][2] = *reinterpret_cast<const uint2*>(vp + (y1c * Wl + x0c) * DH);
      cv[p][3] = *reinterpret_cast<const uint2*>(vp + (y1c * Wl + x1c) * DH);
    }
#pragma unroll
    for (int p = 0; p < 4; p++)
#pragma unroll
      for (int c = 0; c < 4; c++) {
        union { uint2 ui; __half2 h[2]; } cvt;
        cvt.ui = cv[p][c];
        const float2 lo = __half22float2(cvt.h[0]);
        const float2 hi = __half22float2(cvt.h[1]);
        const float wgt = cw[p][c];
        acc.x = fmaf(lo.x, wgt, acc.x);
        acc.y = fmaf(lo.y, wgt, acc.y);
        acc.z = fmaf(hi.x, wgt, acc.z);
        acc.w = fmaf(hi.y, wgt, acc.w);
      }
  }
  *reinterpret_cast<float4*>(out + (size_t)qi * DM + u * 4) = acc;
}

// ---------------------------------------------------------------------------
extern "C" void kernel_launch(void* const* d_in, const int* in_sizes, int n_in,
                              void* d_out, int out_size, void* d_ws, size_t ws_size,
                              hipStream_t stream) {
  const float* query  = (const float*)d_in[0];
  const float* rp     = (const float*)d_in[1];
  const float* val[4] = {(const float*)d_in[2], (const float*)d_in[3],
                         (const float*)d_in[4], (const float*)d_in[5]};
  const float* W_off  = (const float*)d_in[6];
  const float* b_off  = (const float*)d_in[7];
  const float* W_attn = (const float*)d_in[8];
  const float* b_attn = (const float*)d_in[9];
  float* out = (float*)d_out;

  // workspace: vt16[11141120 halves = 22.28MB] | logits[16711680 f32 = 66.8MB]
  //          | Wt[98304 bf16 = 0.197MB]  -> total 89.3MB (<= known-safe 111.4MB)
  __half* vt16  = (__half*)d_ws;
  float* logits = (float*)((char*)d_ws + 11141120ull * sizeof(__half));
  unsigned short* Wt = (unsigned short*)((char*)d_ws +
      11141120ull * sizeof(__half) + 16711680ull * sizeof(float));

  const int HWs[4]   = {16384, 4096, 1024, 256};
  const size_t LB[4] = {0, 8388608, 10485760, 11010048};
  for (int l = 0; l < 4; l++) {
    dim3 g(HWs[l] / 32, 16);
    msda_transpose<<<g, 256, 0, stream>>>(val[l], vt16 + LB[l], HWs[l]);
  }

  msda_cast_w<<<dim3(12, 8), 256, 0, stream>>>(W_off, W_attn, Wt);

  msda_gemm16<<<dim3(NQTOT / 128, 3), 256, 0, stream>>>(
      query, Wt, b_off, b_attn, logits);

  msda_sample<<<dim3(LQ / 4, NB), 256, 0, stream>>>(vt16, logits, rp, out);
}

// Round 12
// 280.740 us; speedup vs baseline: 2.1360x; 1.0071x over previous
//
#include <hip/hip_runtime.h>
#include <hip/hip_fp16.h>
#include <math.h>

// ---- problem constants ----
#define NB     2          // batch
#define LQ     21760      // queries
#define NQTOT  (NB * LQ)  // 43520
#define DM     256        // d_model
#define NH     8          // heads
#define DH     32         // d_head
#define NL     4          // levels
#define NP     4          // points

typedef __attribute__((ext_vector_type(8))) short    bf16x8;
typedef __attribute__((ext_vector_type(4))) float    f32x4;
typedef __attribute__((ext_vector_type(8))) unsigned short ushort8;

// RNE fp32 -> bf16 (bit-level, no API dependence)
__device__ __forceinline__ unsigned short f2bf(float x) {
  union { float f; unsigned int u; } c; c.f = x;
  const unsigned int lsb = (c.u >> 16) & 1u;
  c.u += 0x7fffu + lsb;
  return (unsigned short)(c.u >> 16);
}

// ---------------------------------------------------------------------------
// Kernel 1: fused all-level channel transpose + fp32->fp16
// (byte-identical to round 7 — still awaiting its first measurement)
// ---------------------------------------------------------------------------
__global__ __launch_bounds__(256) void msda_transpose_all(
    const float* __restrict__ v0, const float* __restrict__ v1,
    const float* __restrict__ v2, const float* __restrict__ v3,
    __half* __restrict__ out) {
  __shared__ float ls[32 * 256];
  char* lsb = reinterpret_cast<char*>(ls);

  const int t   = threadIdx.x;
  const int bid = blockIdx.x;
  const int nm  = bid / 85;
  const int r   = bid % 85;
  int l, base;
  if (r < 64)      { l = 0; base = 0;  }
  else if (r < 80) { l = 1; base = 64; }
  else if (r < 84) { l = 2; base = 80; }
  else             { l = 3; base = 84; }
  const int HW   = 16384 >> (2 * l);
  const int pos0 = (r - base) * 256;
  const float* vsrc = (l == 0) ? v0 : (l == 1) ? v1 : (l == 2) ? v2 : v3;
  const size_t LBl  = (l == 0) ? 0ull : (l == 1) ? 8388608ull
                     : (l == 2) ? 10485760ull : 11010048ull;

  // ---- phase 1: global (ch-major) -> LDS (swizzled) ----
  const int ch = t >> 3;   // 0..31
  const int c8 = t & 7;
  const float* ip = vsrc + (size_t)nm * 32 * HW + pos0;
#pragma unroll
  for (int i = 0; i < 8; i++) {
    const int chunk = c8 + 8 * i;            // 16B chunk within 1KB row
    const float4 a = *reinterpret_cast<const float4*>(
        ip + (size_t)ch * HW + chunk * 4);
    const int byte = ch * 1024 + ((chunk * 16) ^ ((ch & 7) << 4));
    *reinterpret_cast<float4*>(lsb + byte) = a;
  }
  __syncthreads();

  // ---- phase 2: LDS -> global (pos-major fp16) ----
  __half2 o[16];
#pragma unroll
  for (int c2 = 0; c2 < 16; c2++) {
    const int ca = 2 * c2, cb = 2 * c2 + 1;
    const float va = *reinterpret_cast<const float*>(
        lsb + ca * 1024 + ((t * 4) ^ ((ca & 7) << 4)));
    const float vb = *reinterpret_cast<const float*>(
        lsb + cb * 1024 + ((t * 4) ^ ((cb & 7) << 4)));
    o[c2] = __floats2half2_rn(va, vb);
  }
  __half* op = out + LBl + ((size_t)nm * HW + pos0 + t) * 32;
#pragma unroll
  for (int k = 0; k < 4; k++) {
    union { __half2 h[4]; float4 f; } pk;
    pk.h[0] = o[4 * k + 0]; pk.h[1] = o[4 * k + 1];
    pk.h[2] = o[4 * k + 2]; pk.h[3] = o[4 * k + 3];
    *reinterpret_cast<float4*>(op + k * 8) = pk.f;
  }
}

// ---------------------------------------------------------------------------
// Kernel 1b: weights -> Wt[384][256] bf16 (unchanged)
// ---------------------------------------------------------------------------
__global__ __launch_bounds__(256) void msda_cast_w(
    const float* __restrict__ W_off, const float* __restrict__ W_attn,
    unsigned short* __restrict__ Wt) {
  __shared__ float tile[32][33];
  const int n0 = blockIdx.x * 32;
  const int k0 = blockIdx.y * 32;
  const int tx = threadIdx.x & 31;
  const int ty = threadIdx.x >> 5;  // 0..7
#pragma unroll
  for (int i = 0; i < 4; i++) {
    const int k = k0 + ty + i * 8;
    const int n = n0 + tx;
    const float v = (blockIdx.x < 8) ? W_off[(size_t)k * 256 + n]
                                     : W_attn[(size_t)k * 128 + (n - 256)];
    tile[ty + i * 8][tx] = v;
  }
  __syncthreads();
#pragma unroll
  for (int i = 0; i < 4; i++) {
    const int nl = ty + i * 8;
    Wt[(size_t)(n0 + nl) * 256 + k0 + tx] = f2bf(tile[tx][nl]);
  }
}

// ---------------------------------------------------------------------------
// Kernel 2: bf16 MFMA GEMM (unchanged from round 5)
// ---------------------------------------------------------------------------
__global__ __launch_bounds__(256) void msda_gemm16(
    const float* __restrict__ Q, const unsigned short* __restrict__ Wt,
    const float* __restrict__ b_off, const float* __restrict__ b_attn,
    float* __restrict__ Cout) {
  __shared__ unsigned short sA[128 * 64];  // [m][k] bf16, swizzled
  __shared__ unsigned short sB[128 * 64];  // [n][k] bf16, swizzled

  const int t    = threadIdx.x;
  const int lane = t & 63;
  const int wid  = t >> 6;
  const int m0   = blockIdx.x * 128;
  const int n0   = blockIdx.y * 128;
  const int wm   = wid >> 1, wn = wid & 1;

  const int sr = t >> 3;  // staging row within 32-row group
  const int sc = t & 7;   // 16B chunk within 128B row

  f32x4 acc[4][4] = {};

  for (int ck = 0; ck < 4; ++ck) {
    const int k0 = ck * 64;
#pragma unroll
    for (int i = 0; i < 4; ++i) {
      const int m = i * 32 + sr;
      const float* src = Q + (size_t)(m0 + m) * DM + k0 + sc * 8;
      const float4 a0 = *reinterpret_cast<const float4*>(src);
      const float4 a1 = *reinterpret_cast<const float4*>(src + 4);
      ushort8 v;
      v[0] = f2bf(a0.x); v[1] = f2bf(a0.y); v[2] = f2bf(a0.z); v[3] = f2bf(a0.w);
      v[4] = f2bf(a1.x); v[5] = f2bf(a1.y); v[6] = f2bf(a1.z); v[7] = f2bf(a1.w);
      const int byte = m * 128 + ((sc * 16) ^ ((m & 7) << 4));
      *reinterpret_cast<ushort8*>(reinterpret_cast<char*>(sA) + byte) = v;
    }
#pragma unroll
    for (int i = 0; i < 4; ++i) {
      const int nr = i * 32 + sr;
      const ushort8 b = *reinterpret_cast<const ushort8*>(
          Wt + (size_t)(n0 + nr) * 256 + k0 + sc * 8);
      const int byte = nr * 128 + ((sc * 16) ^ ((nr & 7) << 4));
      *reinterpret_cast<ushort8*>(reinterpret_cast<char*>(sB) + byte) = b;
    }
    __syncthreads();
#pragma unroll
    for (int ks = 0; ks < 2; ++ks) {
      bf16x8 af[4], bfr[4];
#pragma unroll
      for (int f = 0; f < 4; ++f) {
        const int ar = wm * 64 + f * 16 + (lane & 15);
        const int ab = ar * 128 + ((ks * 64 + (lane >> 4) * 16) ^ ((ar & 7) << 4));
        af[f] = *reinterpret_cast<const bf16x8*>(
            reinterpret_cast<const char*>(sA) + ab);
        const int br = wn * 64 + f * 16 + (lane & 15);
        const int bb = br * 128 + ((ks * 64 + (lane >> 4) * 16) ^ ((br & 7) << 4));
        bfr[f] = *reinterpret_cast<const bf16x8*>(
            reinterpret_cast<const char*>(sB) + bb);
      }
#pragma unroll
      for (int mi = 0; mi < 4; ++mi)
#pragma unroll
        for (int ni = 0; ni < 4; ++ni)
          acc[mi][ni] = __builtin_amdgcn_mfma_f32_16x16x32_bf16(
              af[mi], bfr[ni], acc[mi][ni], 0, 0, 0);
    }
    __syncthreads();
  }

#pragma unroll
  for (int ni = 0; ni < 4; ++ni) {
    const int col = n0 + wn * 64 + ni * 16 + (lane & 15);
    const float bias = (col < 256) ? b_off[col] : b_attn[col - 256];
#pragma unroll
    for (int mi = 0; mi < 4; ++mi) {
      const int row0 = m0 + wm * 64 + mi * 16 + (lane >> 4) * 4;
#pragma unroll
      for (int r = 0; r < 4; ++r)
        Cout[(size_t)(row0 + r) * 384 + col] = acc[mi][ni][r] + bias;
    }
  }
}

// ---------------------------------------------------------------------------
// Kernel 3: softmax + bilinear sampling + weighted sum (fp16 values).
// Weight/address dedup (round-8 design, still awaiting first measurement).
// ---------------------------------------------------------------------------
__global__ __launch_bounds__(256, 3) void msda_sample(
    const __half* __restrict__ vt, const float* __restrict__ logits,
    const float* __restrict__ rp, float* __restrict__ out) {
  __shared__ float Ld[4][384];
  __shared__ float Ew[4][128];
  __shared__ float Aw[4][128];
  __shared__ float Rf[4][8];
  __shared__ float Op[4][NH][36];
  __shared__ float4 Wt4[4][136];   // [w][m*17 + l*4 + p] corner weights
  __shared__ int4   Of4[4][136];   // [w][m*17 + l*4 + p] corner offsets (halves)

  const int t = threadIdx.x;
  const int w = t >> 6;
  const int u = t & 63;
  const int n = blockIdx.y;
  const int q = blockIdx.x * 4 + w;
  const int qi = n * LQ + q;

  const float* lg = logits + (size_t)qi * 384;
  for (int i = u; i < 384; i += 64) Ld[w][i] = lg[i];
  if (u < 8) Rf[w][u] = rp[(size_t)qi * 8 + u];
  __syncthreads();

  // repack offsets into bank-conflict-free layout
#pragma unroll
  for (int r = 0; r < 4; r++) {
    const int j = u + 64 * r;
    const int m = j >> 5, rest = j & 31;
    const int l = rest >> 3, pc = rest & 7;
    Op[w][m][l * 9 + pc] = Ld[w][j];
  }
  // softmax over 16 (l,p) per head
#pragma unroll
  for (int r = 0; r < 2; r++) {
    const int j = u + 64 * r;
    const int h4 = j & ~15;
    float mx = -1e30f;
#pragma unroll
    for (int i = 0; i < 16; i++) mx = fmaxf(mx, Ld[w][256 + h4 + i]);
    Ew[w][j] = __expf(Ld[w][256 + j] - mx);
  }
  __syncthreads();
#pragma unroll
  for (int r = 0; r < 2; r++) {
    const int j = u + 64 * r;
    const int h4 = j & ~15;
    float den = 0.f;
#pragma unroll
    for (int i = 0; i < 16; i++) den += Ew[w][h4 + i];
    Aw[w][j] = Ew[w][j] / den;
  }
  __syncthreads();

  // ---- phase A: per-combo weight/address computation, done ONCE ----
#pragma unroll
  for (int r = 0; r < 2; r++) {
    const int j  = u + 64 * r;          // 0..127 = m*16 + l*4 + p
    const int m  = j >> 4;
    const int lp = j & 15;
    const int l  = lp >> 2;
    const int p  = j & 3;
    const int sh = 7 - l;               // Wl = 1 << sh
    const int Wl = 1 << sh;
    const float fx = fmaf(Rf[w][2 * l + 0], (float)Wl, -0.5f);
    const float fy = fmaf(Rf[w][2 * l + 1], (float)Wl, -0.5f);
    const float ox = Op[w][m][l * 9 + 2 * p + 0];
    const float oy = Op[w][m][l * 9 + 2 * p + 1];
    const float aw = Aw[w][j];
    const float xp = fx + ox;
    const float yp = fy + oy;
    const float x0f = floorf(xp), y0f = floorf(yp);
    const float wx = xp - x0f, wy = yp - y0f;
    const int x0 = (int)x0f, y0 = (int)y0f;
    const int x1 = x0 + 1,   y1 = y0 + 1;
    const float vx0 = ((unsigned)x0 < (unsigned)Wl) ? 1.f : 0.f;
    const float vx1 = ((unsigned)x1 < (unsigned)Wl) ? 1.f : 0.f;
    const float vy0 = ((unsigned)y0 < (unsigned)Wl) ? 1.f : 0.f;
    const float vy1 = ((unsigned)y1 < (unsigned)Wl) ? 1.f : 0.f;
    const int x0c = min(max(x0, 0), Wl - 1), x1c = min(max(x1, 0), Wl - 1);
    const int y0c = min(max(y0, 0), Wl - 1), y1c = min(max(y1, 0), Wl - 1);
    const int idx = m * 17 + lp;
    Wt4[w][idx] = make_float4(aw * (1.f - wx) * (1.f - wy) * vx0 * vy0,
                              aw * wx * (1.f - wy) * vx1 * vy0,
                              aw * (1.f - wx) * wy * vx0 * vy1,
                              aw * wx * wy * vx1 * vy1);
    Of4[w][idx] = make_int4(((y0c << sh) + x0c) << 5,
                            ((y0c << sh) + x1c) << 5,
                            ((y1c << sh) + x0c) << 5,
                            ((y1c << sh) + x1c) << 5);
  }
  __syncthreads();

  // ---- phase B: loads + FMA (core unchanged; weights/offsets from LDS) ----
  const int m = u >> 3;
  const int d0 = (u & 7) * 4;  // halves
  float4 acc; acc.x = acc.y = acc.z = acc.w = 0.f;

  const size_t LB[4] = {0, 8388608, 10485760, 11010048};
#pragma unroll
  for (int l = 0; l < 4; l++) {
    const int HW = (128 >> l) * (128 >> l);
    const __half* vp = vt + LB[l] + ((size_t)(n * NH + m) * HW) * DH + d0;

    uint2  cv[4][4];
    float4 w4[4];
#pragma unroll
    for (int p = 0; p < 4; p++) {
      const int idx = m * 17 + l * 4 + p;
      w4[p] = Wt4[w][idx];
      const int4 o4 = Of4[w][idx];
      cv[p][0] = *reinterpret_cast<const uint2*>(vp + o4.x);
      cv[p][1] = *reinterpret_cast<const uint2*>(vp + o4.y);
      cv[p][2] = *reinterpret_cast<const uint2*>(vp + o4.z);
      cv[p][3] = *reinterpret_cast<const uint2*>(vp + o4.w);
    }
#pragma unroll
    for (int p = 0; p < 4; p++) {
      const float cw[4] = {w4[p].x, w4[p].y, w4[p].z, w4[p].w};
#pragma unroll
      for (int c = 0; c < 4; c++) {
        union { uint2 ui; __half2 h[2]; } cvt;
        cvt.ui = cv[p][c];
        const float2 lo = __half22float2(cvt.h[0]);
        const float2 hi = __half22float2(cvt.h[1]);
        const float wgt = cw[c];
        acc.x = fmaf(lo.x, wgt, acc.x);
        acc.y = fmaf(lo.y, wgt, acc.y);
        acc.z = fmaf(hi.x, wgt, acc.z);
        acc.w = fmaf(hi.y, wgt, acc.w);
      }
    }
  }
  *reinterpret_cast<float4*>(out + (size_t)qi * DM + u * 4) = acc;
}

// ---------------------------------------------------------------------------
extern "C" void kernel_launch(void* const* d_in, const int* in_sizes, int n_in,
                              void* d_out, int out_size, void* d_ws, size_t ws_size,
                              hipStream_t stream) {
  const float* query  = (const float*)d_in[0];
  const float* rp     = (const float*)d_in[1];
  const float* W_off  = (const float*)d_in[6];
  const float* b_off  = (const float*)d_in[7];
  const float* W_attn = (const float*)d_in[8];
  const float* b_attn = (const float*)d_in[9];
  float* out = (float*)d_out;

  // workspace: vt16[11141120 halves = 22.28MB] | logits[16711680 f32 = 66.8MB]
  //          | Wt[98304 bf16 = 0.197MB]  -> total 89.3MB
  __half* vt16  = (__half*)d_ws;
  float* logits = (float*)((char*)d_ws + 11141120ull * sizeof(__half));
  unsigned short* Wt = (unsigned short*)((char*)d_ws +
      11141120ull * sizeof(__half) + 16711680ull * sizeof(float));

  msda_transpose_all<<<dim3(85 * 16), 256, 0, stream>>>(
      (const float*)d_in[2], (const float*)d_in[3],
      (const float*)d_in[4], (const float*)d_in[5], vt16);

  msda_cast_w<<<dim3(12, 8), 256, 0, stream>>>(W_off, W_attn, Wt);

  msda_gemm16<<<dim3(NQTOT / 128, 3), 256, 0, stream>>>(
      query, Wt, b_off, b_attn, logits);

  msda_sample<<<dim3(LQ / 4, NB), 256, 0, stream>>>(vt16, logits, rp, out);
}